// Round 1
// baseline (814.927 us; speedup 1.0000x reference)
//
#include <hip/hip_runtime.h>
#include <math.h>

#define N_ROWS 262144
#define DIM 64
#define K_CODES 1024
#define EPSF 1e-12f

// ws layout (floats): [0, K*D) = normalized codebook wn
//                     [K*D, K*D+K) = sw (sum of wn^2 per code)
//                     [K*D+K, K*D+K+1024) = per-block loss partials

__global__ __launch_bounds__(64) void normalize_codebook_kernel(
    const float* __restrict__ w, float* __restrict__ wn, float* __restrict__ sw)
{
    int k = blockIdx.x;
    int d = threadIdx.x;
    float v = w[k * DIM + d];
    float sq = v * v;
    #pragma unroll
    for (int off = 32; off; off >>= 1) sq += __shfl_xor(sq, off, 64);
    float n = fmaxf(sqrtf(sq), EPSF);
    float o = v / n;
    wn[k * DIM + d] = o;
    float s2 = o * o;
    #pragma unroll
    for (int off = 32; off; off >>= 1) s2 += __shfl_xor(s2, off, 64);
    if (d == 0) sw[k] = s2;
}

__global__ __launch_bounds__(256) void vq_main_kernel(
    const float* __restrict__ x,
    const float* __restrict__ wn,
    const float* __restrict__ sw,
    float* __restrict__ out_q,    // [N*D]
    float* __restrict__ out_idx,  // [N]   (as float values)
    float* __restrict__ partial)  // [gridDim.x]
{
    const int row = blockIdx.x * 256 + threadIdx.x;

    // ---- load x row, normalize into registers ----
    float xv[DIM];
    const float4* xp = (const float4*)(x + (size_t)row * DIM);
    #pragma unroll
    for (int i = 0; i < 16; ++i) {
        float4 t = xp[i];
        xv[4 * i + 0] = t.x; xv[4 * i + 1] = t.y;
        xv[4 * i + 2] = t.z; xv[4 * i + 3] = t.w;
    }
    float ss = 0.f;
    #pragma unroll
    for (int d = 0; d < DIM; ++d) ss += xv[d] * xv[d];
    float n = fmaxf(sqrtf(ss), EPSF);
    #pragma unroll
    for (int d = 0; d < DIM; ++d) xv[d] = xv[d] / n;

    // ---- scan codebook: argmin of sw[k] - 2*dot ----
    float best = 3.4e38f;
    int bk = 0;
    for (int k = 0; k < K_CODES; ++k) {
        const float4* wp = (const float4*)(wn + k * DIM);
        float a0 = 0.f, a1 = 0.f, a2 = 0.f, a3 = 0.f;
        #pragma unroll
        for (int i = 0; i < 16; ++i) {
            float4 t = wp[i];
            a0 = fmaf(xv[4 * i + 0], t.x, a0);
            a1 = fmaf(xv[4 * i + 1], t.y, a1);
            a2 = fmaf(xv[4 * i + 2], t.z, a2);
            a3 = fmaf(xv[4 * i + 3], t.w, a3);
        }
        float dot = (a0 + a1) + (a2 + a3);
        float score = fmaf(-2.f, dot, sw[k]);
        if (score < best) { best = score; bk = k; }  // strict < keeps first min (matches argmin)
    }

    // ---- gather quantized row, write, accumulate loss partial ----
    const float4* qp = (const float4*)(wn + (size_t)bk * DIM);
    float4* oq = (float4*)(out_q + (size_t)row * DIM);
    float ls = 0.f;
    #pragma unroll
    for (int i = 0; i < 16; ++i) {
        float4 t = qp[i];
        float d0 = t.x - xv[4 * i + 0];
        float d1 = t.y - xv[4 * i + 1];
        float d2 = t.z - xv[4 * i + 2];
        float d3 = t.w - xv[4 * i + 3];
        ls += d0 * d0 + d1 * d1 + d2 * d2 + d3 * d3;
        oq[i] = t;
    }
    out_idx[row] = (float)bk;

    // ---- deterministic block reduction of loss partial ----
    #pragma unroll
    for (int off = 32; off; off >>= 1) ls += __shfl_xor(ls, off, 64);
    __shared__ float red[4];
    int lane = threadIdx.x & 63;
    int wid = threadIdx.x >> 6;
    if (lane == 0) red[wid] = ls;
    __syncthreads();
    if (threadIdx.x == 0)
        partial[blockIdx.x] = (red[0] + red[1]) + (red[2] + red[3]);
}

__global__ __launch_bounds__(64) void finalize_kernel(
    const float* __restrict__ partial, float* __restrict__ loss_out)
{
    int t = threadIdx.x;
    float s = 0.f;
    #pragma unroll
    for (int i = 0; i < 16; ++i) s += partial[t * 16 + i];  // fixed order
    #pragma unroll
    for (int off = 32; off; off >>= 1) s += __shfl_xor(s, off, 64);
    if (t == 0)
        *loss_out = 1.25f * (s / (float)((size_t)N_ROWS * DIM));
}

extern "C" void kernel_launch(void* const* d_in, const int* in_sizes, int n_in,
                              void* d_out, int out_size, void* d_ws, size_t ws_size,
                              hipStream_t stream) {
    const float* x = (const float*)d_in[0];        // [N, D]
    const float* w = (const float*)d_in[1];        // [K, D]
    float* out = (float*)d_out;
    float* ws = (float*)d_ws;

    float* wn = ws;                        // K*D
    float* sw = ws + (size_t)K_CODES * DIM;  // K
    float* partial = sw + K_CODES;           // 1024

    float* out_q = out;                                   // [N*D]
    float* out_loss = out + (size_t)N_ROWS * DIM;         // [1]
    float* out_idx = out_loss + 1;                        // [N]

    normalize_codebook_kernel<<<K_CODES, 64, 0, stream>>>(w, wn, sw);
    vq_main_kernel<<<N_ROWS / 256, 256, 0, stream>>>(x, wn, sw, out_q, out_idx, partial);
    finalize_kernel<<<1, 64, 0, stream>>>(partial, out_loss);
}

// Round 2
// 141.473 us; speedup vs baseline: 5.7603x; 5.7603x over previous
//
#include <hip/hip_runtime.h>
#include <math.h>

#define N_ROWS 262144
#define DIM 64
#define K_CODES 1024
#define EPSF 1e-12f
#define NTILES 64            // K_CODES / 16
#define ROWS_PER_BLOCK 128
#define ROWS_PER_WAVE 32

typedef _Float16 f16x8 __attribute__((ext_vector_type(8)));
typedef float f32x4 __attribute__((ext_vector_type(4)));

// ws layout:
//   wn      : float[K*D]        normalized codebook (fp32, for gather/epilogue)
//   sw      : float[K]          sum of wn^2 per code
//   partial : float[2048]       per-block loss partials
//   wf      : _Float16[K*D*2]   codebook hi/lo f16, MFMA-B-fragment ordered
//             layout: [tile t][h(hi/lo)][kstep s][lane][i]  (512 halves per (t,h,s))

__global__ __launch_bounds__(64) void prep_codebook(
    const float* __restrict__ w, float* __restrict__ wn, float* __restrict__ sw,
    _Float16* __restrict__ wf)
{
    int k = blockIdx.x;
    int d = threadIdx.x;
    float v = w[k * DIM + d];
    float sq = v * v;
    #pragma unroll
    for (int off = 32; off; off >>= 1) sq += __shfl_xor(sq, off, 64);
    float n = fmaxf(sqrtf(sq), EPSF);
    float o = v / n;
    wn[k * DIM + d] = o;
    float s2 = o * o;
    #pragma unroll
    for (int off = 32; off; off >>= 1) s2 += __shfl_xor(s2, off, 64);
    if (d == 0) sw[k] = s2;

    _Float16 hi = (_Float16)o;
    _Float16 lo = (_Float16)(o - (float)hi);
    // B-fragment position: lane = g*16 + (k&15), element i, for k-dim d = s*32+g*8+i
    int t = k >> 4, nn = k & 15, s = d >> 5, g = (d >> 3) & 3, i = d & 7;
    size_t base = (size_t)t * 2048 + (size_t)s * 512 + (size_t)(g * 16 + nn) * 8 + i;
    wf[base] = hi;          // h = 0
    wf[base + 1024] = lo;   // h = 1
}

__global__ __launch_bounds__(256) void vq_main_kernel(
    const float* __restrict__ x,
    const float* __restrict__ wn,
    const float* __restrict__ sw,
    const _Float16* __restrict__ wf,
    float* __restrict__ out_q,
    float* __restrict__ out_idx,
    float* __restrict__ partial)
{
    __shared__ int   idx_lds[ROWS_PER_BLOCK];
    __shared__ float n_lds[ROWS_PER_BLOCK];
    __shared__ float red[4];

    const int tid  = threadIdx.x;
    const int w    = tid >> 6;
    const int lane = tid & 63;
    const int nidx = lane & 15;
    const int g    = lane >> 4;

    const int block_row0 = blockIdx.x * ROWS_PER_BLOCK;
    const int wave_row0  = block_row0 + w * ROWS_PER_WAVE;

    // ---- build hi/lo f16 A-fragments for 2 row-tiles of 16 rows ----
    // A layout (16x16x32): lane holds A[m=lane&15][k = (lane>>4)*8 + i], kstep s adds s*32
    f16x8 ah[2][2], al[2][2];
    #pragma unroll
    for (int rt = 0; rt < 2; ++rt) {
        const int row = wave_row0 + rt * 16 + nidx;
        float xv[2][8];
        #pragma unroll
        for (int s = 0; s < 2; ++s) {
            const float4* p = (const float4*)(x + (size_t)row * DIM + s * 32 + g * 8);
            float4 q0 = p[0], q1 = p[1];
            xv[s][0] = q0.x; xv[s][1] = q0.y; xv[s][2] = q0.z; xv[s][3] = q0.w;
            xv[s][4] = q1.x; xv[s][5] = q1.y; xv[s][6] = q1.z; xv[s][7] = q1.w;
        }
        float ss = 0.f;
        #pragma unroll
        for (int s = 0; s < 2; ++s)
            #pragma unroll
            for (int e = 0; e < 8; ++e) ss += xv[s][e] * xv[s][e];
        ss += __shfl_xor(ss, 16, 64);
        ss += __shfl_xor(ss, 32, 64);
        float nrm = fmaxf(sqrtf(ss), EPSF);
        if (g == 0) n_lds[w * ROWS_PER_WAVE + rt * 16 + nidx] = nrm;
        #pragma unroll
        for (int s = 0; s < 2; ++s)
            #pragma unroll
            for (int e = 0; e < 8; ++e) {
                float v = xv[s][e] / nrm;
                _Float16 hi = (_Float16)v;
                ah[rt][s][e] = hi;
                al[rt][s][e] = (_Float16)(v - (float)hi);
            }
    }

    float best[2][4];
    int   bidx[2][4];
    #pragma unroll
    for (int rt = 0; rt < 2; ++rt)
        #pragma unroll
        for (int r = 0; r < 4; ++r) { best[rt][r] = 3.4e38f; bidx[rt][r] = 0; }

    // ---- scan codebook in 16-code tiles ----
    for (int t = 0; t < NTILES; ++t) {
        const _Float16* bp = wf + (size_t)t * 2048 + (size_t)lane * 8;
        f16x8 bh0 = *(const f16x8*)(bp);
        f16x8 bh1 = *(const f16x8*)(bp + 512);
        f16x8 bl0 = *(const f16x8*)(bp + 1024);
        f16x8 bl1 = *(const f16x8*)(bp + 1536);
        float sval = sw[t * 16 + nidx];

        f32x4 acc0 = {0.f, 0.f, 0.f, 0.f};
        f32x4 acc1 = {0.f, 0.f, 0.f, 0.f};
        acc0 = __builtin_amdgcn_mfma_f32_16x16x32_f16(ah[0][0], bh0, acc0, 0, 0, 0);
        acc1 = __builtin_amdgcn_mfma_f32_16x16x32_f16(ah[1][0], bh0, acc1, 0, 0, 0);
        acc0 = __builtin_amdgcn_mfma_f32_16x16x32_f16(ah[0][1], bh1, acc0, 0, 0, 0);
        acc1 = __builtin_amdgcn_mfma_f32_16x16x32_f16(ah[1][1], bh1, acc1, 0, 0, 0);
        acc0 = __builtin_amdgcn_mfma_f32_16x16x32_f16(ah[0][0], bl0, acc0, 0, 0, 0);
        acc1 = __builtin_amdgcn_mfma_f32_16x16x32_f16(ah[1][0], bl0, acc1, 0, 0, 0);
        acc0 = __builtin_amdgcn_mfma_f32_16x16x32_f16(ah[0][1], bl1, acc0, 0, 0, 0);
        acc1 = __builtin_amdgcn_mfma_f32_16x16x32_f16(ah[1][1], bl1, acc1, 0, 0, 0);
        acc0 = __builtin_amdgcn_mfma_f32_16x16x32_f16(al[0][0], bh0, acc0, 0, 0, 0);
        acc1 = __builtin_amdgcn_mfma_f32_16x16x32_f16(al[1][0], bh0, acc1, 0, 0, 0);
        acc0 = __builtin_amdgcn_mfma_f32_16x16x32_f16(al[0][1], bh1, acc0, 0, 0, 0);
        acc1 = __builtin_amdgcn_mfma_f32_16x16x32_f16(al[1][1], bh1, acc1, 0, 0, 0);

        const int colbase = t * 16 + nidx;
        #pragma unroll
        for (int r = 0; r < 4; ++r) {
            float s0 = fmaf(-2.f, acc0[r], sval);
            if (s0 < best[0][r]) { best[0][r] = s0; bidx[0][r] = colbase; }
            float s1 = fmaf(-2.f, acc1[r], sval);
            if (s1 < best[1][r]) { best[1][r] = s1; bidx[1][r] = colbase; }
        }
    }

    // ---- argmin reduce across the 16 lanes holding each output row ----
    // C layout: col = lane&15, row = (lane>>4)*4 + r  → row lives in 16 lanes (same lane>>4)
    #pragma unroll
    for (int rt = 0; rt < 2; ++rt)
        #pragma unroll
        for (int r = 0; r < 4; ++r) {
            float b = best[rt][r];
            int   i0 = bidx[rt][r];
            #pragma unroll
            for (int off = 1; off <= 8; off <<= 1) {
                float ob = __shfl_xor(b, off, 64);
                int   oi = __shfl_xor(i0, off, 64);
                if (ob < b || (ob == b && oi < i0)) { b = ob; i0 = oi; }
            }
            best[rt][r] = b;
            bidx[rt][r] = i0;
        }
    if (nidx == 0) {
        #pragma unroll
        for (int rt = 0; rt < 2; ++rt)
            #pragma unroll
            for (int r = 0; r < 4; ++r)
                idx_lds[w * ROWS_PER_WAVE + rt * 16 + g * 4 + r] = bidx[rt][r];
    }
    __syncthreads();

    // ---- epilogue: gather fp32 codebook row, write out, loss partial ----
    const int lr   = tid >> 1;                      // local row 0..127
    const int grow = block_row0 + lr;
    const int d0   = (tid & 1) * 32;
    const int ci   = idx_lds[lr];
    const float nrm = n_lds[lr];
    const float4* xp = (const float4*)(x  + (size_t)grow * DIM + d0);
    const float4* qp = (const float4*)(wn + (size_t)ci   * DIM + d0);
    float4* op = (float4*)(out_q + (size_t)grow * DIM + d0);
    float ls = 0.f;
    #pragma unroll
    for (int i = 0; i < 8; ++i) {
        float4 qv = qp[i];
        float4 xv = xp[i];
        float e0 = qv.x - xv.x / nrm;
        float e1 = qv.y - xv.y / nrm;
        float e2 = qv.z - xv.z / nrm;
        float e3 = qv.w - xv.w / nrm;
        ls += e0 * e0 + e1 * e1 + e2 * e2 + e3 * e3;
        op[i] = qv;
    }
    if (!(tid & 1)) out_idx[grow] = (float)ci;

    float s = ls;
    #pragma unroll
    for (int off = 32; off; off >>= 1) s += __shfl_xor(s, off, 64);
    if (lane == 0) red[w] = s;
    __syncthreads();
    if (tid == 0) partial[blockIdx.x] = (red[0] + red[1]) + (red[2] + red[3]);
}

__global__ __launch_bounds__(256) void finalize_kernel(
    const float* __restrict__ partial, float* __restrict__ loss_out)
{
    __shared__ float red[4];
    int t = threadIdx.x;
    float s = 0.f;
    #pragma unroll
    for (int i = 0; i < 8; ++i) s += partial[t * 8 + i];  // fixed order
    #pragma unroll
    for (int off = 32; off; off >>= 1) s += __shfl_xor(s, off, 64);
    if ((t & 63) == 0) red[t >> 6] = s;
    __syncthreads();
    if (t == 0)
        *loss_out = 1.25f * (((red[0] + red[1]) + (red[2] + red[3]))
                             / (float)((size_t)N_ROWS * DIM));
}

extern "C" void kernel_launch(void* const* d_in, const int* in_sizes, int n_in,
                              void* d_out, int out_size, void* d_ws, size_t ws_size,
                              hipStream_t stream) {
    const float* x = (const float*)d_in[0];   // [N, D]
    const float* w = (const float*)d_in[1];   // [K, D]
    float* out = (float*)d_out;
    float* ws = (float*)d_ws;

    float* wn      = ws;                                   // K*D floats
    float* sw      = wn + (size_t)K_CODES * DIM;           // K floats
    float* partial = sw + K_CODES;                         // 2048 floats
    _Float16* wf   = (_Float16*)(partial + 2048);          // K*D*2 halves

    float* out_q    = out;                                 // [N*D]
    float* out_loss = out + (size_t)N_ROWS * DIM;          // [1]
    float* out_idx  = out_loss + 1;                        // [N]

    prep_codebook<<<K_CODES, 64, 0, stream>>>(w, wn, sw, wf);
    vq_main_kernel<<<N_ROWS / ROWS_PER_BLOCK, 256, 0, stream>>>(
        x, wn, sw, wf, out_q, out_idx, partial);
    finalize_kernel<<<1, 256, 0, stream>>>(partial, out_loss);
}

// Round 3
// 136.282 us; speedup vs baseline: 5.9797x; 1.0381x over previous
//
#include <hip/hip_runtime.h>
#include <math.h>

#define N_ROWS 262144
#define DIM 64
#define K_CODES 1024
#define NT 32                 // code tiles of 32
#define ROWS_PER_BLOCK 128
#define EPSF 1e-12f

typedef _Float16 f16x8 __attribute__((ext_vector_type(8)));
typedef float f32x16 __attribute__((ext_vector_type(16)));

// ws layout (floats):
//   wn      : [0, 65536)          normalized codebook fp32 (for gather/epilogue)
//   msw     : [65536, 66560)      -0.5 * sum(wn^2) per code
//   partial : [66560, 68608)      per-block loss partials
//   wf      : halves after that   codebook hi/lo f16, 32x32x16 B-fragment order
//             [tile t][h][kstep s][lane][i]  : half = t*4096 + h*2048 + s*512 + lane*8 + i

__global__ __launch_bounds__(64) void prep_codebook(
    const float* __restrict__ w, float* __restrict__ wn,
    float* __restrict__ msw, _Float16* __restrict__ wf)
{
    int k = blockIdx.x;
    int d = threadIdx.x;
    float v = w[k * DIM + d];
    float sq = v * v;
    #pragma unroll
    for (int off = 32; off; off >>= 1) sq += __shfl_xor(sq, off, 64);
    float n = fmaxf(sqrtf(sq), EPSF);
    float o = v / n;
    wn[k * DIM + d] = o;
    float s2 = o * o;
    #pragma unroll
    for (int off = 32; off; off >>= 1) s2 += __shfl_xor(s2, off, 64);
    if (d == 0) msw[k] = -0.5f * s2;

    _Float16 hi = (_Float16)o;
    _Float16 lo = (_Float16)(o - (float)hi);
    // B fragment for 32x32x16: lane = g*32 + n holds dims d = s*16 + g*8 + i of code n
    int t = k >> 5, nn = k & 31, s = d >> 4, g = (d >> 3) & 1, i = d & 7;
    size_t base = (size_t)t * 4096 + (size_t)s * 512 + (size_t)(g * 32 + nn) * 8 + i;
    wf[base] = hi;           // h = 0
    wf[base + 2048] = lo;    // h = 1
}

#define BODY(T, CW0, CW1, NL0, NL1)                                           \
  {                                                                           \
    const int cur = (T) & 1;                                                  \
    const _Float16* bp = &bbuf[cur][lane * 8];                                \
    f16x8 bh0 = *(const f16x8*)(bp);                                          \
    f16x8 bh1 = *(const f16x8*)(bp + 512);                                    \
    f16x8 bh2 = *(const f16x8*)(bp + 1024);                                   \
    f16x8 bh3 = *(const f16x8*)(bp + 1536);                                   \
    f16x8 bl0 = *(const f16x8*)(bp + 2048);                                   \
    f16x8 bl1 = *(const f16x8*)(bp + 2560);                                   \
    f16x8 bl2 = *(const f16x8*)(bp + 3072);                                   \
    f16x8 bl3 = *(const f16x8*)(bp + 3584);                                   \
    float mval = msw_lds[(T) * 32 + col];                                     \
    if ((T) + 1 < NT) {                                                       \
      *(f16x8*)&bbuf[cur ^ 1][tid * 16] = CW0;                                \
      *(f16x8*)&bbuf[cur ^ 1][tid * 16 + 8] = CW1;                            \
    }                                                                         \
    if ((T) + 2 < NT) {                                                       \
      NL0 = wf8[((T) + 2) * 512 + tid * 2];                                   \
      NL1 = wf8[((T) + 2) * 512 + tid * 2 + 1];                               \
    }                                                                         \
    f32x16 acc;                                                               \
    _Pragma("unroll")                                                         \
    for (int e = 0; e < 16; ++e) acc[e] = mval;                               \
    acc = __builtin_amdgcn_mfma_f32_32x32x16_f16(ah[0], bh0, acc, 0, 0, 0);   \
    acc = __builtin_amdgcn_mfma_f32_32x32x16_f16(ah[1], bh1, acc, 0, 0, 0);   \
    acc = __builtin_amdgcn_mfma_f32_32x32x16_f16(ah[2], bh2, acc, 0, 0, 0);   \
    acc = __builtin_amdgcn_mfma_f32_32x32x16_f16(ah[3], bh3, acc, 0, 0, 0);   \
    acc = __builtin_amdgcn_mfma_f32_32x32x16_f16(ah[0], bl0, acc, 0, 0, 0);   \
    acc = __builtin_amdgcn_mfma_f32_32x32x16_f16(ah[1], bl1, acc, 0, 0, 0);   \
    acc = __builtin_amdgcn_mfma_f32_32x32x16_f16(ah[2], bl2, acc, 0, 0, 0);   \
    acc = __builtin_amdgcn_mfma_f32_32x32x16_f16(ah[3], bl3, acc, 0, 0, 0);   \
    acc = __builtin_amdgcn_mfma_f32_32x32x16_f16(al[0], bh0, acc, 0, 0, 0);   \
    acc = __builtin_amdgcn_mfma_f32_32x32x16_f16(al[1], bh1, acc, 0, 0, 0);   \
    acc = __builtin_amdgcn_mfma_f32_32x32x16_f16(al[2], bh2, acc, 0, 0, 0);   \
    acc = __builtin_amdgcn_mfma_f32_32x32x16_f16(al[3], bh3, acc, 0, 0, 0);   \
    _Pragma("unroll")                                                         \
    for (int e = 0; e < 16; ++e)                                              \
      if (acc[e] > best[e]) { best[e] = acc[e]; bt[e] = (T); }                \
    __syncthreads();                                                          \
  }

__global__ __launch_bounds__(256, 3) void vq_main_kernel(
    const float* __restrict__ x,
    const float* __restrict__ wn,
    const float* __restrict__ msw,
    const _Float16* __restrict__ wf,
    float* __restrict__ out_q,
    float* __restrict__ out_idx,
    float* __restrict__ partial)
{
    __shared__ _Float16 bbuf[2][4096];          // 2 x 8 KB code tiles
    __shared__ float msw_lds[K_CODES];
    __shared__ int idx_lds[ROWS_PER_BLOCK];
    __shared__ float inv_lds[ROWS_PER_BLOCK];
    __shared__ float red[4];

    const int tid = threadIdx.x;
    const int wv = tid >> 6;
    const int lane = tid & 63;
    const int col = lane & 31;
    const int g = lane >> 5;
    const int block_row0 = blockIdx.x * ROWS_PER_BLOCK;

    // ---- prologue: load + normalize 32 rows/wave, build hi/lo A-fragments ----
    // A for 32x32x16: lane holds A[m=lane&31][k=(lane>>5)*8+i], kstep s → dims s*16+g*8+i
    f16x8 ah[4], al[4];
    {
        const int arow = block_row0 + wv * 32 + col;
        const float* xrow = x + (size_t)arow * DIM + g * 8;
        float xv[4][8];
        #pragma unroll
        for (int s = 0; s < 4; ++s) {
            float4 q0 = *(const float4*)(xrow + s * 16);
            float4 q1 = *(const float4*)(xrow + s * 16 + 4);
            xv[s][0] = q0.x; xv[s][1] = q0.y; xv[s][2] = q0.z; xv[s][3] = q0.w;
            xv[s][4] = q1.x; xv[s][5] = q1.y; xv[s][6] = q1.z; xv[s][7] = q1.w;
        }
        float ss = 0.f;
        #pragma unroll
        for (int s = 0; s < 4; ++s)
            #pragma unroll
            for (int i = 0; i < 8; ++i) ss += xv[s][i] * xv[s][i];
        ss += __shfl_xor(ss, 32, 64);   // partner lane holds the row's other 32 dims
        float nrm = fmaxf(sqrtf(ss), EPSF);
        float inv = 1.0f / nrm;
        if (g == 0) inv_lds[wv * 32 + col] = inv;
        #pragma unroll
        for (int s = 0; s < 4; ++s)
            #pragma unroll
            for (int i = 0; i < 8; ++i) {
                float v = xv[s][i] * inv;
                _Float16 hi = (_Float16)v;
                ah[s][i] = hi;
                al[s][i] = (_Float16)(v - (float)hi);
            }
    }

    // ---- stage msw into LDS ----
    {
        float4 mv = *(const float4*)(msw + tid * 4);
        *(float4*)&msw_lds[tid * 4] = mv;
    }

    // ---- staging prologue: tile 0 → bbuf[0]; tile 1 → regs ----
    const f16x8* wf8 = (const f16x8*)wf;
    f16x8 sA0, sA1, sB0, sB1;
    sB0 = wf8[tid * 2];
    sB1 = wf8[tid * 2 + 1];
    *(f16x8*)&bbuf[0][tid * 16] = sB0;
    *(f16x8*)&bbuf[0][tid * 16 + 8] = sB1;
    sA0 = wf8[512 + tid * 2];
    sA1 = wf8[512 + tid * 2 + 1];
    __syncthreads();

    float best[16];
    int bt[16];
    #pragma unroll
    for (int e = 0; e < 16; ++e) { best[e] = -3.4e38f; bt[e] = 0; }

    // ---- main loop: 32 code tiles, double-buffered ----
    for (int tt = 0; tt < NT; tt += 2) {
        BODY(tt, sA0, sA1, sB0, sB1)
        BODY(tt + 1, sB0, sB1, sA0, sA1)
    }

    // ---- argmax reduce across the 32 lanes holding each row ----
    // C/D 32x32: col = lane&31, row = (e&3) + 8*(e>>2) + 4*(lane>>5)
    #pragma unroll
    for (int e = 0; e < 16; ++e) {
        float b = best[e];
        int bi = bt[e] * 32 + col;
        #pragma unroll
        for (int off = 1; off <= 16; off <<= 1) {
            float ob = __shfl_xor(b, off, 64);
            int oi = __shfl_xor(bi, off, 64);
            if (ob > b || (ob == b && oi < bi)) { b = ob; bi = oi; }
        }
        if (col == 0)
            idx_lds[wv * 32 + (e & 3) + 8 * (e >> 2) + 4 * g] = bi;
    }
    __syncthreads();

    // ---- epilogue: gather fp32 codebook row, write out, loss partial ----
    const int lr = tid >> 1;
    const int grow = block_row0 + lr;
    const int d0 = (tid & 1) * 32;
    const int ci = idx_lds[lr];
    const float invn = inv_lds[lr];
    const float4* xp = (const float4*)(x + (size_t)grow * DIM + d0);
    const float4* qp = (const float4*)(wn + (size_t)ci * DIM + d0);
    float4* op = (float4*)(out_q + (size_t)grow * DIM + d0);
    float ls = 0.f;
    #pragma unroll
    for (int i = 0; i < 8; ++i) {
        float4 qv = qp[i];
        float4 xv4 = xp[i];
        float e0 = qv.x - xv4.x * invn;
        float e1 = qv.y - xv4.y * invn;
        float e2 = qv.z - xv4.z * invn;
        float e3 = qv.w - xv4.w * invn;
        ls += e0 * e0 + e1 * e1 + e2 * e2 + e3 * e3;
        op[i] = qv;
    }
    if (!(tid & 1)) out_idx[grow] = (float)ci;

    float s = ls;
    #pragma unroll
    for (int off = 32; off; off >>= 1) s += __shfl_xor(s, off, 64);
    if (lane == 0) red[wv] = s;
    __syncthreads();
    if (tid == 0) partial[blockIdx.x] = (red[0] + red[1]) + (red[2] + red[3]);
}

__global__ __launch_bounds__(256) void finalize_kernel(
    const float* __restrict__ partial, float* __restrict__ loss_out)
{
    __shared__ float red[4];
    int t = threadIdx.x;
    float s = 0.f;
    #pragma unroll
    for (int i = 0; i < 8; ++i) s += partial[t * 8 + i];  // fixed order
    #pragma unroll
    for (int off = 32; off; off >>= 1) s += __shfl_xor(s, off, 64);
    if ((t & 63) == 0) red[t >> 6] = s;
    __syncthreads();
    if (t == 0)
        *loss_out = 1.25f * (((red[0] + red[1]) + (red[2] + red[3]))
                             / (float)((size_t)N_ROWS * DIM));
}

extern "C" void kernel_launch(void* const* d_in, const int* in_sizes, int n_in,
                              void* d_out, int out_size, void* d_ws, size_t ws_size,
                              hipStream_t stream) {
    const float* x = (const float*)d_in[0];   // [N, D]
    const float* w = (const float*)d_in[1];   // [K, D]
    float* out = (float*)d_out;
    float* ws = (float*)d_ws;

    float* wn      = ws;                                   // 65536 floats
    float* msw     = wn + (size_t)K_CODES * DIM;           // 1024 floats
    float* partial = msw + K_CODES;                        // 2048 floats
    _Float16* wf   = (_Float16*)(partial + 2048);          // 131072 halves (256 KB)

    float* out_q    = out;                                 // [N*D]
    float* out_loss = out + (size_t)N_ROWS * DIM;          // [1]
    float* out_idx  = out_loss + 1;                        // [N]

    prep_codebook<<<K_CODES, 64, 0, stream>>>(w, wn, msw, wf);
    vq_main_kernel<<<N_ROWS / ROWS_PER_BLOCK, 256, 0, stream>>>(
        x, wn, msw, wf, out_q, out_idx, partial);
    finalize_kernel<<<1, 256, 0, stream>>>(partial, out_loss);
}